// Round 2
// baseline (279.059 us; speedup 1.0000x reference)
//
#include <hip/hip_runtime.h>

constexpr int B  = 8;
constexpr int C  = 256;
constexpr int HW = 128 * 128;   // 16384 px per plane
constexpr int K  = 64;

typedef float vf4 __attribute__((ext_vector_type(4)));

// fast uncert: s = 1/(1+e^-x); u = -s*log(s+1e-6)
// v_exp + v_rcp + v_log (~12 cyc) instead of precise ocml exp/log/div (~60+)
__device__ __forceinline__ float uncert_fast(float x) {
    float t = __expf(-x);
    float s = __builtin_amdgcn_rcpf(1.0f + t);
    return -s * __logf(s + 1e-6f);
}

// Kernel 1: score[b,c] = mean over 16K-px plane of uncert(x). One block/plane.
__global__ __launch_bounds__(256) void score_kernel(const float* __restrict__ x,
                                                    float* __restrict__ score) {
    const int plane = blockIdx.x;                 // b*C + c
    const float4* xp = (const float4*)(x + (size_t)plane * HW);
    const int t = threadIdx.x;

    float acc = 0.0f;
#pragma unroll
    for (int i = 0; i < 16; ++i) {
        float4 v = xp[t + i * 256];
        acc += uncert_fast(v.x) + uncert_fast(v.y) + uncert_fast(v.z) + uncert_fast(v.w);
    }
#pragma unroll
    for (int off = 32; off > 0; off >>= 1) acc += __shfl_down(acc, off, 64);

    __shared__ float sm[4];
    if ((t & 63) == 0) sm[t >> 6] = acc;
    __syncthreads();
    if (t == 0) score[plane] = (sm[0] + sm[1] + sm[2] + sm[3]) * (1.0f / HW);
}

// Kernel 2 (fused): per (b, 256-px chunk) block:
//  (a) rank 256 scores in-block (stable ascending == lax.top_k(-score) order)
//  (b) attn = sigmoid(b + sum_k w[k]*x[b,sel[k],px])  -- k-loop split over 4 waves
//  (c) out[b,c,px] = x[b,c,px] * attn[px] for all 256 c, NT stores (keep x in LLC)
__global__ __launch_bounds__(256) void fused_kernel(
    const float* __restrict__ x, const float* __restrict__ score,
    const float* __restrict__ w, const float* __restrict__ bias,
    float* __restrict__ out)
{
    const int b     = blockIdx.x >> 6;            // 0..7
    const int chunk = blockIdx.x & 63;            // 0..63
    const int t  = threadIdx.x;
    const int wv = t >> 6, ln = t & 63;

    __shared__ float sc[C];
    __shared__ float wsh[K];
    __shared__ int   chs[K];
    __shared__ vf4   part[4][64];
    __shared__ vf4   attn_s[64];

    sc[t] = score[b * C + t];
    if (t < K) wsh[t] = w[t];
    __syncthreads();

    {   // stable ascending rank of this thread's channel
        const float my = sc[t];
        int rank = 0;
#pragma unroll 16
        for (int j = 0; j < C; ++j) {
            float o = sc[j];
            rank += (o < my) || (o == my && j < t);
        }
        if (rank < K) chs[rank] = t;
    }
    __syncthreads();

    const float* xb = x + (size_t)b * C * HW;
    const int p4 = (chunk << 6) + ln;             // float4 index within a plane

    // (b) attn partials: wave wv covers k = wv*16 .. wv*16+15
    vf4 acc = (vf4)0.0f;
#pragma unroll
    for (int kk = 0; kk < 16; ++kk) {
        const int k = (wv << 4) + kk;
        const float wk = wsh[k];
        vf4 v = ((const vf4*)(xb + (size_t)chs[k] * HW))[p4];
        acc += wk * v;
    }
    part[wv][ln] = acc;
    __syncthreads();

    if (wv == 0) {
        vf4 a = part[0][ln] + part[1][ln] + part[2][ln] + part[3][ln];
        const float b0 = bias[0];
        vf4 o;
        o.x = __builtin_amdgcn_rcpf(1.0f + __expf(-(a.x + b0)));
        o.y = __builtin_amdgcn_rcpf(1.0f + __expf(-(a.y + b0)));
        o.z = __builtin_amdgcn_rcpf(1.0f + __expf(-(a.z + b0)));
        o.w = __builtin_amdgcn_rcpf(1.0f + __expf(-(a.w + b0)));
        attn_s[ln] = o;
    }
    __syncthreads();
    const vf4 am = attn_s[ln];

    // (c) broadcast multiply: wave wv streams channels wv*64 .. wv*64+63
    const vf4* xb4 = (const vf4*)xb;
    vf4* ob4 = (vf4*)(out + (size_t)b * C * HW);
#pragma unroll 4
    for (int j = 0; j < 64; ++j) {
        const int c = (wv << 6) + j;
        const size_t idx = (size_t)c * (HW / 4) + p4;
        vf4 v = xb4[idx];
        vf4 o = v * am;
        __builtin_nontemporal_store(o, ob4 + idx);
    }
}

extern "C" void kernel_launch(void* const* d_in, const int* in_sizes, int n_in,
                              void* d_out, int out_size, void* d_ws, size_t ws_size,
                              hipStream_t stream) {
    const float* x    = (const float*)d_in[0];
    const float* w    = (const float*)d_in[1];
    const float* bias = (const float*)d_in[2];
    float* out = (float*)d_out;

    float* score = (float*)d_ws;                 // 2048 floats

    score_kernel<<<B * C, 256, 0, stream>>>(x, score);
    fused_kernel<<<B * 64, 256, 0, stream>>>(x, score, w, bias, out);
}

// Round 3
// 276.847 us; speedup vs baseline: 1.0080x; 1.0080x over previous
//
#include <hip/hip_runtime.h>

constexpr int B  = 8;
constexpr int C  = 256;
constexpr int HW = 128 * 128;   // 16384 px per plane
constexpr int K  = 64;

typedef float vf4 __attribute__((ext_vector_type(4)));

// fast uncert: s = 1/(1+e^-x); u = -s*log(s+1e-6)
__device__ __forceinline__ float uncert_fast(float x) {
    float t = __expf(-x);
    float s = __builtin_amdgcn_rcpf(1.0f + t);
    return -s * __logf(s + 1e-6f);
}

// Kernel 1: score[b,c] = plane mean of uncert(x). One block per plane.
// Memory-bound: 134 MB cold HBM read ~21 us; VALU (exp/rcp/log) ~6 us, hidden.
__global__ __launch_bounds__(256) void score_kernel(const float* __restrict__ x,
                                                    float* __restrict__ score) {
    const int plane = blockIdx.x;
    const float4* xp = (const float4*)(x + (size_t)plane * HW);
    const int t = threadIdx.x;

    float acc = 0.0f;
#pragma unroll
    for (int i = 0; i < 16; ++i) {
        float4 v = xp[t + i * 256];
        acc += uncert_fast(v.x) + uncert_fast(v.y) + uncert_fast(v.z) + uncert_fast(v.w);
    }
#pragma unroll
    for (int off = 32; off > 0; off >>= 1) acc += __shfl_down(acc, off, 64);

    __shared__ float sm[4];
    if ((t & 63) == 0) sm[t >> 6] = acc;
    __syncthreads();
    if (t == 0) score[plane] = (sm[0] + sm[1] + sm[2] + sm[3]) * (1.0f / HW);
}

// Kernel 2 (fused): per (b, chunk) block:
//  (a) stable ascending rank of 256 scores (== lax.top_k(-score) order)
//  (b) attn = sigmoid(b0 + sum_k w[k]*x[b,sel[k],px]), k split over 4 waves
//  (c) out = x * attn for all 256 channels; NT stores keep x LLC-resident
__global__ __launch_bounds__(256) void fused_kernel(
    const float* __restrict__ x, const float* __restrict__ score,
    const float* __restrict__ w, const float* __restrict__ bias,
    float* __restrict__ out)
{
    const int b     = blockIdx.x >> 6;            // 0..7
    const int chunk = blockIdx.x & 63;            // 0..63
    const int t  = threadIdx.x;
    const int wv = t >> 6, ln = t & 63;

    __shared__ __align__(16) float sc[C];
    __shared__ float wsh[K];
    __shared__ int   chs[K];
    __shared__ vf4   part[4][64];
    __shared__ vf4   attn_s[64];

    sc[t] = score[b * C + t];
    if (t < K) wsh[t] = w[t];
    __syncthreads();

    {   // rank via broadcast float4 LDS reads (same addr all lanes -> free)
        const float my = sc[t];
        const vf4* sc4 = (const vf4*)sc;
        int rank = 0;
#pragma unroll 8
        for (int j4 = 0; j4 < C / 4; ++j4) {
            vf4 o = sc4[j4];
            const int j = j4 << 2;
            rank += (o.x < my) || (o.x == my && (j + 0) < t);
            rank += (o.y < my) || (o.y == my && (j + 1) < t);
            rank += (o.z < my) || (o.z == my && (j + 2) < t);
            rank += (o.w < my) || (o.w == my && (j + 3) < t);
        }
        if (rank < K) chs[rank] = t;
    }
    __syncthreads();

    const float* xb = x + (size_t)b * C * HW;
    const int p4 = (chunk << 6) + ln;             // float4 index within plane

    // (b) attn partials: wave wv covers k = wv*16 .. wv*16+15
    vf4 acc = (vf4)0.0f;
#pragma unroll
    for (int kk = 0; kk < 16; ++kk) {
        const int k = (wv << 4) + kk;
        const float wk = wsh[k];
        vf4 v = ((const vf4*)(xb + (size_t)chs[k] * HW))[p4];
        acc += wk * v;
    }
    part[wv][ln] = acc;
    __syncthreads();

    if (wv == 0) {
        vf4 a = part[0][ln] + part[1][ln] + part[2][ln] + part[3][ln];
        const float b0 = bias[0];
        vf4 o;
        o.x = __builtin_amdgcn_rcpf(1.0f + __expf(-(a.x + b0)));
        o.y = __builtin_amdgcn_rcpf(1.0f + __expf(-(a.y + b0)));
        o.z = __builtin_amdgcn_rcpf(1.0f + __expf(-(a.z + b0)));
        o.w = __builtin_amdgcn_rcpf(1.0f + __expf(-(a.w + b0)));
        attn_s[ln] = o;
    }
    __syncthreads();
    const vf4 am = attn_s[ln];

    // (c) stream all 256 channels for this pixel chunk
    const vf4* xb4 = (const vf4*)xb;
    vf4* ob4 = (vf4*)(out + (size_t)b * C * HW);
    size_t idx = (size_t)(wv << 6) * (HW / 4) + p4;
#pragma unroll 8
    for (int j = 0; j < 64; ++j, idx += HW / 4) {
        vf4 v = xb4[idx];
        __builtin_nontemporal_store(v * am, ob4 + idx);
    }
}

extern "C" void kernel_launch(void* const* d_in, const int* in_sizes, int n_in,
                              void* d_out, int out_size, void* d_ws, size_t ws_size,
                              hipStream_t stream) {
    const float* x    = (const float*)d_in[0];
    const float* w    = (const float*)d_in[1];
    const float* bias = (const float*)d_in[2];
    float* out = (float*)d_out;

    float* score = (float*)d_ws;                 // 2048 floats

    score_kernel<<<B * C, 256, 0, stream>>>(x, score);
    fused_kernel<<<B * 64, 256, 0, stream>>>(x, score, w, bias, out);
}